// Round 1
// baseline (551.034 us; speedup 1.0000x reference)
//
#include <hip/hip_runtime.h>
#include <hip/hip_bf16.h>

typedef __attribute__((ext_vector_type(4))) float f32x4;
typedef __attribute__((ext_vector_type(8))) short bf16x8;

#define VOCAB 32000
#define DIMS 1024
#define BATCH 2
#define SEQ 2048
#define ROWS (BATCH * SEQ)  // 4096
#define NC 128              // cumsum chunks per sequence
#define CL 16               // chunk length; NC*CL == SEQ

// ---------- helpers ----------
static __device__ __forceinline__ unsigned short f2bf(float f) {
  // round-to-nearest-even f32 -> bf16 (inputs are well-behaved, no NaN path)
  unsigned int u = __float_as_uint(f);
  unsigned int r = u + 0x7fffu + ((u >> 16) & 1u);
  return (unsigned short)(r >> 16);
}

// ---------- fp32 -> bf16 bulk convert ----------
__global__ void cvt_f32_bf16(const float* __restrict__ src,
                             unsigned short* __restrict__ dst, int n4) {
  int i = blockIdx.x * blockDim.x + threadIdx.x;
  int stride = gridDim.x * blockDim.x;
  for (; i < n4; i += stride) {
    float4 v = ((const float4*)src)[i];
    ushort4 o = {f2bf(v.x), f2bf(v.y), f2bf(v.z), f2bf(v.w)};
    ((ushort4*)dst)[i] = o;
  }
}

// ---------- embedding gather + convert ----------
__global__ void gather_emb(const int* __restrict__ idx,
                           const float* __restrict__ emb,
                           unsigned short* __restrict__ eB) {
  const int row = blockIdx.x;   // 0..ROWS-1
  const int t = threadIdx.x;    // 256 threads, 4 floats each
  const int token = idx[row];
  const float4* src = (const float4*)(emb + (size_t)token * DIMS);
  float4 v = src[t];
  ushort4 o = {f2bf(v.x), f2bf(v.y), f2bf(v.z), f2bf(v.w)};
  ((ushort4*)(eB + (size_t)row * DIMS))[t] = o;
}

// ---------- NT bf16 GEMM: C[m][n] = sum_k A[m][k]*B[n][k] (+bias[n]) ----------
// 128x128 tile, BK=32, 256 threads = 4 waves in 2x2, each wave 64x64 via
// 4x4 frags of mfma_f32_16x16x32_bf16. global_load_lds(16B) staging.
__global__ __launch_bounds__(256) void gemm_bt(
    const unsigned short* __restrict__ A,  // [M][K] bf16, K-contiguous
    const unsigned short* __restrict__ B,  // [N][K] bf16, K-contiguous
    float* __restrict__ C,                 // [M][ldC] fp32
    const float* __restrict__ bias,        // [>=N] fp32 or nullptr
    int K, int ldC) {
  __shared__ __align__(16) unsigned short sA[128 * 32];
  __shared__ __align__(16) unsigned short sB[128 * 32];

  const int tid = threadIdx.x;
  const int lane = tid & 63;
  const int w = tid >> 6;  // wave 0..3
  const int wr = w >> 1;   // wave row 0..1
  const int wc = w & 1;    // wave col 0..1
  const long mBase = (long)blockIdx.y * 128;
  const long nBase = (long)blockIdx.x * 128;

  const unsigned short* Ati = A + mBase * K;
  const unsigned short* Bti = B + nBase * K;

  // staging geometry: wave w instr i covers tile rows [w*32+i*16, +16),
  // lane l -> row + (l>>2), k-elems (l&3)*8 .. +8  (16B per lane)
  const int srow0 = w * 32;
  const int sr = lane >> 2;
  const int ske = (lane & 3) * 8;

  f32x4 acc[4][4] = {};

  for (int kt = 0; kt < K; kt += 32) {
    __syncthreads();  // previous iter's LDS reads done before overwrite
#pragma unroll
    for (int i = 0; i < 2; ++i) {
      const int r = srow0 + i * 16;
      __builtin_amdgcn_global_load_lds(
          (const __attribute__((address_space(1))) unsigned int*)(
              Ati + (long)(r + sr) * K + kt + ske),
          (__attribute__((address_space(3))) unsigned int*)(&sA[r * 32]),
          16, 0, 0);
      __builtin_amdgcn_global_load_lds(
          (const __attribute__((address_space(1))) unsigned int*)(
              Bti + (long)(r + sr) * K + kt + ske),
          (__attribute__((address_space(3))) unsigned int*)(&sB[r * 32]),
          16, 0, 0);
    }
    __syncthreads();  // drains vmcnt, LDS tile ready

    bf16x8 af[4], bfr[4];
#pragma unroll
    for (int mi = 0; mi < 4; ++mi)
      af[mi] = *(const bf16x8*)&sA[(wr * 64 + mi * 16 + (lane & 15)) * 32 +
                                   8 * (lane >> 4)];
#pragma unroll
    for (int ni = 0; ni < 4; ++ni)
      bfr[ni] = *(const bf16x8*)&sB[(wc * 64 + ni * 16 + (lane & 15)) * 32 +
                                    8 * (lane >> 4)];
#pragma unroll
    for (int mi = 0; mi < 4; ++mi)
#pragma unroll
      for (int ni = 0; ni < 4; ++ni)
        acc[mi][ni] = __builtin_amdgcn_mfma_f32_16x16x32_bf16(
            af[mi], bfr[ni], acc[mi][ni], 0, 0, 0);
  }

  // epilogue: C/D frag mapping col=lane&15, row=4*(lane>>4)+reg   [m89]
  const int rq = lane >> 4;
  const int cl = lane & 15;
#pragma unroll
  for (int ni = 0; ni < 4; ++ni) {
    const long c = nBase + wc * 64 + ni * 16 + cl;
    const float bv = bias ? bias[c] : 0.0f;
#pragma unroll
    for (int mi = 0; mi < 4; ++mi) {
      const long r = mBase + wr * 64 + mi * 16 + rq * 4;
#pragma unroll
      for (int j = 0; j < 4; ++j)
        C[(r + j) * (long)ldC + c] = acc[mi][ni][j] + bv;
    }
  }
}

// ---------- causal cumulative mean (chunked scan) ----------
// partial layout: [BATCH][DIMS][NC] f32
__global__ void chunk_sums(const float* __restrict__ V,
                           float* __restrict__ part) {
  const int bc = blockIdx.x;  // b*NC + c
  const int b = bc >> 7;
  const int c = bc & (NC - 1);
  const int d0 = threadIdx.x * 4;
  const float* vp = V + ((size_t)b * SEQ + (size_t)c * CL) * DIMS + d0;
  float4 s = {0.f, 0.f, 0.f, 0.f};
#pragma unroll
  for (int l = 0; l < CL; ++l) {
    float4 v = *(const float4*)(vp + (size_t)l * DIMS);
    s.x += v.x; s.y += v.y; s.z += v.z; s.w += v.w;
  }
  float* pp = part + ((size_t)b * DIMS + d0) * NC + c;
  pp[0 * NC] = s.x; pp[1 * NC] = s.y; pp[2 * NC] = s.z; pp[3 * NC] = s.w;
}

__global__ void chunk_scan(float* __restrict__ part) {
  const int g = blockIdx.x * blockDim.x + threadIdx.x;  // 0..BATCH*DIMS-1
  float* p = part + (size_t)g * NC;
  float run = 0.f;
#pragma unroll 4
  for (int c = 0; c < NC; ++c) {
    float t = p[c];
    p[c] = run;
    run += t;
  }
}

__global__ void cum_avg(const float* __restrict__ V,
                        const float* __restrict__ part,
                        unsigned short* __restrict__ avgB) {
  const int bc = blockIdx.x;
  const int b = bc >> 7;
  const int c = bc & (NC - 1);
  const int d0 = threadIdx.x * 4;
  const float* pp = part + ((size_t)b * DIMS + d0) * NC + c;
  float4 run = {pp[0 * NC], pp[1 * NC], pp[2 * NC], pp[3 * NC]};
  const float* vp = V + ((size_t)b * SEQ + (size_t)c * CL) * DIMS + d0;
  unsigned short* op = avgB + ((size_t)b * SEQ + (size_t)c * CL) * DIMS + d0;
#pragma unroll
  for (int l = 0; l < CL; ++l) {
    float4 v = *(const float4*)(vp + (size_t)l * DIMS);
    run.x += v.x; run.y += v.y; run.z += v.z; run.w += v.w;
    const float inv = 1.0f / (float)(c * CL + l + 1);
    ushort4 o = {f2bf(run.x * inv), f2bf(run.y * inv), f2bf(run.z * inv),
                 f2bf(run.w * inv)};
    *(ushort4*)(op + (size_t)l * DIMS) = o;
  }
}

// ---------- workspace layout (bytes, 256-aligned) ----------
#define WS_EB 0UL                   // bf16 [4096][1024]   8,388,608
#define WS_WV 8388608UL             // bf16 [1024][1024]   2,097,152
#define WS_WO 10485760UL            // bf16 [32000][1024] 65,536,000
#define WS_V 76021760UL             // f32  [4096][1024]  16,777,216
#define WS_AVG 92798976UL           // bf16 [4096][1024]   8,388,608
#define WS_PART 101187584UL         // f32  [2][1024][128] 1,048,576
#define WS_NEED 102236160UL

extern "C" void kernel_launch(void* const* d_in, const int* in_sizes, int n_in,
                              void* d_out, int out_size, void* d_ws,
                              size_t ws_size, hipStream_t stream) {
  const int* idx = (const int*)d_in[0];
  const float* emb = (const float*)d_in[1];
  const float* W_V = (const float*)d_in[2];
  const float* W_out = (const float*)d_in[3];
  const float* b_out = (const float*)d_in[4];
  float* out = (float*)d_out;

  if (ws_size < WS_NEED) return;  // leaves poison -> loud validation failure

  char* ws = (char*)d_ws;
  unsigned short* eB = (unsigned short*)(ws + WS_EB);
  unsigned short* wvB = (unsigned short*)(ws + WS_WV);
  unsigned short* woB = (unsigned short*)(ws + WS_WO);
  float* V = (float*)(ws + WS_V);
  unsigned short* avgB = (unsigned short*)(ws + WS_AVG);
  float* part = (float*)(ws + WS_PART);

  // 1) weight converts + embedding gather
  hipLaunchKernelGGL(cvt_f32_bf16, dim3(1024), dim3(256), 0, stream, W_V, wvB,
                     (DIMS * DIMS) / 4);
  hipLaunchKernelGGL(cvt_f32_bf16, dim3(2048), dim3(256), 0, stream, W_out,
                     woB, (VOCAB * DIMS) / 4);
  hipLaunchKernelGGL(gather_emb, dim3(ROWS), dim3(256), 0, stream, idx, emb,
                     eB);
  // 2) V = e @ W_V^T   (M=4096, N=1024, K=1024)
  hipLaunchKernelGGL(gemm_bt, dim3(DIMS / 128, ROWS / 128), dim3(256), 0,
                     stream, eB, wvB, V, (const float*)nullptr, DIMS, DIMS);
  // 3) causal cumulative mean -> bf16
  hipLaunchKernelGGL(chunk_sums, dim3(BATCH * NC), dim3(256), 0, stream, V,
                     part);
  hipLaunchKernelGGL(chunk_scan, dim3((BATCH * DIMS) / 256), dim3(256), 0,
                     stream, part);
  hipLaunchKernelGGL(cum_avg, dim3(BATCH * NC), dim3(256), 0, stream, V, part,
                     avgB);
  // 4) out = avg @ W_out^T + b_out   (M=4096, N=32000, K=1024)
  hipLaunchKernelGGL(gemm_bt, dim3(VOCAB / 128, ROWS / 128), dim3(256), 0,
                     stream, avgB, woB, out, b_out, DIMS, VOCAB);
}

// Round 2
// 544.692 us; speedup vs baseline: 1.0116x; 1.0116x over previous
//
#include <hip/hip_runtime.h>
#include <hip/hip_bf16.h>

typedef __attribute__((ext_vector_type(4))) float f32x4;
typedef __attribute__((ext_vector_type(8))) short bf16x8;

#define VOCAB 32000
#define DIMS 1024
#define BATCH 2
#define SEQ 2048
#define ROWS (BATCH * SEQ)  // 4096
#define NC 128              // cumsum chunks per sequence
#define CL 16               // chunk length; NC*CL == SEQ

// ---------- helpers ----------
static __device__ __forceinline__ unsigned short f2bf(float f) {
  // round-to-nearest-even f32 -> bf16 (inputs are well-behaved, no NaN path)
  unsigned int u = __float_as_uint(f);
  unsigned int r = u + 0x7fffu + ((u >> 16) & 1u);
  return (unsigned short)(r >> 16);
}

// ---------- fp32 -> bf16 bulk convert ----------
__global__ void cvt_f32_bf16(const float* __restrict__ src,
                             unsigned short* __restrict__ dst, int n4) {
  int i = blockIdx.x * blockDim.x + threadIdx.x;
  int stride = gridDim.x * blockDim.x;
  for (; i < n4; i += stride) {
    float4 v = ((const float4*)src)[i];
    ushort4 o = {f2bf(v.x), f2bf(v.y), f2bf(v.z), f2bf(v.w)};
    ((ushort4*)dst)[i] = o;
  }
}

// ---------- embedding gather + convert ----------
__global__ void gather_emb(const int* __restrict__ idx,
                           const float* __restrict__ emb,
                           unsigned short* __restrict__ eB) {
  const int row = blockIdx.x;   // 0..ROWS-1
  const int t = threadIdx.x;    // 256 threads, 4 floats each
  const int token = idx[row];
  const float4* src = (const float4*)(emb + (size_t)token * DIMS);
  float4 v = src[t];
  ushort4 o = {f2bf(v.x), f2bf(v.y), f2bf(v.z), f2bf(v.w)};
  ((ushort4*)(eB + (size_t)row * DIMS))[t] = o;
}

// ---------- NT bf16 GEMM: C[m][n] = sum_k A[m][k]*B[n][k] (+bias[n]) ----------
// 128x128 tile, BK=32, 256 threads = 4 waves in 2x2, each wave 64x64 via
// 4x4 frags of mfma_f32_16x16x32_bf16. global_load_lds(16B) staging.
// GRID: x = m-tile (small dim, fastest), y = n-tile. This keeps the
// concurrent B working-set small so W_out streams from HBM exactly once
// (round-1 counter evidence: n-fastest order over-fetched W_out 17x).
__global__ __launch_bounds__(256) void gemm_bt(
    const unsigned short* __restrict__ A,  // [M][K] bf16, K-contiguous
    const unsigned short* __restrict__ B,  // [N][K] bf16, K-contiguous
    float* __restrict__ C,                 // [M][ldC] fp32
    const float* __restrict__ bias,        // [>=N] fp32 or nullptr
    int K, int ldC) {
  __shared__ __align__(16) unsigned short sA[128 * 32];
  __shared__ __align__(16) unsigned short sB[128 * 32];

  const int tid = threadIdx.x;
  const int lane = tid & 63;
  const int w = tid >> 6;  // wave 0..3
  const int wr = w >> 1;   // wave row 0..1
  const int wc = w & 1;    // wave col 0..1
  const long mBase = (long)blockIdx.x * 128;
  const long nBase = (long)blockIdx.y * 128;

  const unsigned short* Ati = A + mBase * K;
  const unsigned short* Bti = B + nBase * K;

  // staging geometry: wave w instr i covers tile rows [w*32+i*16, +16),
  // lane l -> row + (l>>2), k-elems (l&3)*8 .. +8  (16B per lane)
  const int srow0 = w * 32;
  const int sr = lane >> 2;
  const int ske = (lane & 3) * 8;

  f32x4 acc[4][4] = {};

  for (int kt = 0; kt < K; kt += 32) {
    __syncthreads();  // previous iter's LDS reads done before overwrite
#pragma unroll
    for (int i = 0; i < 2; ++i) {
      const int r = srow0 + i * 16;
      __builtin_amdgcn_global_load_lds(
          (const __attribute__((address_space(1))) unsigned int*)(
              Ati + (long)(r + sr) * K + kt + ske),
          (__attribute__((address_space(3))) unsigned int*)(&sA[r * 32]),
          16, 0, 0);
      __builtin_amdgcn_global_load_lds(
          (const __attribute__((address_space(1))) unsigned int*)(
              Bti + (long)(r + sr) * K + kt + ske),
          (__attribute__((address_space(3))) unsigned int*)(&sB[r * 32]),
          16, 0, 0);
    }
    __syncthreads();  // drains vmcnt, LDS tile ready

    bf16x8 af[4], bfr[4];
#pragma unroll
    for (int mi = 0; mi < 4; ++mi)
      af[mi] = *(const bf16x8*)&sA[(wr * 64 + mi * 16 + (lane & 15)) * 32 +
                                   8 * (lane >> 4)];
#pragma unroll
    for (int ni = 0; ni < 4; ++ni)
      bfr[ni] = *(const bf16x8*)&sB[(wc * 64 + ni * 16 + (lane & 15)) * 32 +
                                    8 * (lane >> 4)];
#pragma unroll
    for (int mi = 0; mi < 4; ++mi)
#pragma unroll
      for (int ni = 0; ni < 4; ++ni)
        acc[mi][ni] = __builtin_amdgcn_mfma_f32_16x16x32_bf16(
            af[mi], bfr[ni], acc[mi][ni], 0, 0, 0);
  }

  // epilogue: C/D frag mapping col=lane&15, row=4*(lane>>4)+reg   [m89]
  const int rq = lane >> 4;
  const int cl = lane & 15;
#pragma unroll
  for (int ni = 0; ni < 4; ++ni) {
    const long c = nBase + wc * 64 + ni * 16 + cl;
    const float bv = bias ? bias[c] : 0.0f;
#pragma unroll
    for (int mi = 0; mi < 4; ++mi) {
      const long r = mBase + wr * 64 + mi * 16 + rq * 4;
#pragma unroll
      for (int j = 0; j < 4; ++j)
        C[(r + j) * (long)ldC + c] = acc[mi][ni][j] + bv;
    }
  }
}

// ---------- causal cumulative mean (chunked scan) ----------
// partial layout: [BATCH][DIMS][NC] f32
__global__ void chunk_sums(const float* __restrict__ V,
                           float* __restrict__ part) {
  const int bc = blockIdx.x;  // b*NC + c
  const int b = bc >> 7;
  const int c = bc & (NC - 1);
  const int d0 = threadIdx.x * 4;
  const float* vp = V + ((size_t)b * SEQ + (size_t)c * CL) * DIMS + d0;
  float4 s = {0.f, 0.f, 0.f, 0.f};
#pragma unroll
  for (int l = 0; l < CL; ++l) {
    float4 v = *(const float4*)(vp + (size_t)l * DIMS);
    s.x += v.x; s.y += v.y; s.z += v.z; s.w += v.w;
  }
  float* pp = part + ((size_t)b * DIMS + d0) * NC + c;
  pp[0 * NC] = s.x; pp[1 * NC] = s.y; pp[2 * NC] = s.z; pp[3 * NC] = s.w;
}

__global__ void chunk_scan(float* __restrict__ part) {
  const int g = blockIdx.x * blockDim.x + threadIdx.x;  // 0..BATCH*DIMS-1
  float* p = part + (size_t)g * NC;
  float run = 0.f;
#pragma unroll 4
  for (int c = 0; c < NC; ++c) {
    float t = p[c];
    p[c] = run;
    run += t;
  }
}

__global__ void cum_avg(const float* __restrict__ V,
                        const float* __restrict__ part,
                        unsigned short* __restrict__ avgB) {
  const int bc = blockIdx.x;
  const int b = bc >> 7;
  const int c = bc & (NC - 1);
  const int d0 = threadIdx.x * 4;
  const float* pp = part + ((size_t)b * DIMS + d0) * NC + c;
  float4 run = {pp[0 * NC], pp[1 * NC], pp[2 * NC], pp[3 * NC]};
  const float* vp = V + ((size_t)b * SEQ + (size_t)c * CL) * DIMS + d0;
  unsigned short* op = avgB + ((size_t)b * SEQ + (size_t)c * CL) * DIMS + d0;
#pragma unroll
  for (int l = 0; l < CL; ++l) {
    float4 v = *(const float4*)(vp + (size_t)l * DIMS);
    run.x += v.x; run.y += v.y; run.z += v.z; run.w += v.w;
    const float inv = 1.0f / (float)(c * CL + l + 1);
    ushort4 o = {f2bf(run.x * inv), f2bf(run.y * inv), f2bf(run.z * inv),
                 f2bf(run.w * inv)};
    *(ushort4*)(op + (size_t)l * DIMS) = o;
  }
}

// ---------- workspace layout (bytes, 256-aligned) ----------
#define WS_EB 0UL                   // bf16 [4096][1024]   8,388,608
#define WS_WV 8388608UL             // bf16 [1024][1024]   2,097,152
#define WS_WO 10485760UL            // bf16 [32000][1024] 65,536,000
#define WS_V 76021760UL             // f32  [4096][1024]  16,777,216
#define WS_AVG 92798976UL           // bf16 [4096][1024]   8,388,608
#define WS_PART 101187584UL         // f32  [2][1024][128] 1,048,576
#define WS_NEED 102236160UL

extern "C" void kernel_launch(void* const* d_in, const int* in_sizes, int n_in,
                              void* d_out, int out_size, void* d_ws,
                              size_t ws_size, hipStream_t stream) {
  const int* idx = (const int*)d_in[0];
  const float* emb = (const float*)d_in[1];
  const float* W_V = (const float*)d_in[2];
  const float* W_out = (const float*)d_in[3];
  const float* b_out = (const float*)d_in[4];
  float* out = (float*)d_out;

  if (ws_size < WS_NEED) return;  // leaves poison -> loud validation failure

  char* ws = (char*)d_ws;
  unsigned short* eB = (unsigned short*)(ws + WS_EB);
  unsigned short* wvB = (unsigned short*)(ws + WS_WV);
  unsigned short* woB = (unsigned short*)(ws + WS_WO);
  float* V = (float*)(ws + WS_V);
  unsigned short* avgB = (unsigned short*)(ws + WS_AVG);
  float* part = (float*)(ws + WS_PART);

  // 1) weight converts + embedding gather
  hipLaunchKernelGGL(cvt_f32_bf16, dim3(1024), dim3(256), 0, stream, W_V, wvB,
                     (DIMS * DIMS) / 4);
  hipLaunchKernelGGL(cvt_f32_bf16, dim3(2048), dim3(256), 0, stream, W_out,
                     woB, (VOCAB * DIMS) / 4);
  hipLaunchKernelGGL(gather_emb, dim3(ROWS), dim3(256), 0, stream, idx, emb,
                     eB);
  // 2) V = e @ W_V^T   (M=4096, N=1024, K=1024) — grid x = m-tiles
  hipLaunchKernelGGL(gemm_bt, dim3(ROWS / 128, DIMS / 128), dim3(256), 0,
                     stream, eB, wvB, V, (const float*)nullptr, DIMS, DIMS);
  // 3) causal cumulative mean -> bf16
  hipLaunchKernelGGL(chunk_sums, dim3(BATCH * NC), dim3(256), 0, stream, V,
                     part);
  hipLaunchKernelGGL(chunk_scan, dim3((BATCH * DIMS) / 256), dim3(256), 0,
                     stream, part);
  hipLaunchKernelGGL(cum_avg, dim3(BATCH * NC), dim3(256), 0, stream, V, part,
                     avgB);
  // 4) out = avg @ W_out^T + b_out   (M=4096, N=32000, K=1024)
  //    grid x = m-tiles (32, fastest) so concurrent blocks share ~20
  //    n-columns: B working set ~5 MB, W_out streams once.
  hipLaunchKernelGGL(gemm_bt, dim3(ROWS / 128, VOCAB / 128), dim3(256), 0,
                     stream, avgB, woB, out, b_out, DIMS, VOCAB);
}

// Round 3
// 505.563 us; speedup vs baseline: 1.0899x; 1.0774x over previous
//
#include <hip/hip_runtime.h>
#include <hip/hip_bf16.h>

typedef __attribute__((ext_vector_type(4))) float f32x4;
typedef __attribute__((ext_vector_type(8))) short bf16x8;

#define VOCAB 32000
#define DIMS 1024
#define BATCH 2
#define SEQ 2048
#define ROWS (BATCH * SEQ)  // 4096
#define NC 128              // cumsum chunks per sequence
#define CL 16               // chunk length; NC*CL == SEQ

// ---------- helpers ----------
static __device__ __forceinline__ unsigned short f2bf(float f) {
  unsigned int u = __float_as_uint(f);
  unsigned int r = u + 0x7fffu + ((u >> 16) & 1u);
  return (unsigned short)(r >> 16);
}

// ---------- fp32 -> bf16 bulk convert ----------
__global__ void cvt_f32_bf16(const float* __restrict__ src,
                             unsigned short* __restrict__ dst, int n4) {
  int i = blockIdx.x * blockDim.x + threadIdx.x;
  int stride = gridDim.x * blockDim.x;
  for (; i < n4; i += stride) {
    float4 v = ((const float4*)src)[i];
    ushort4 o = {f2bf(v.x), f2bf(v.y), f2bf(v.z), f2bf(v.w)};
    ((ushort4*)dst)[i] = o;
  }
}

// ---------- embedding gather + convert ----------
__global__ void gather_emb(const int* __restrict__ idx,
                           const float* __restrict__ emb,
                           unsigned short* __restrict__ eB) {
  const int row = blockIdx.x;
  const int t = threadIdx.x;
  const int token = idx[row];
  const float4* src = (const float4*)(emb + (size_t)token * DIMS);
  float4 v = src[t];
  ushort4 o = {f2bf(v.x), f2bf(v.y), f2bf(v.z), f2bf(v.w)};
  ((ushort4*)(eB + (size_t)row * DIMS))[t] = o;
}

// ---------- old 128x128 NT GEMM (kept for the small V projection) ----------
__global__ __launch_bounds__(256) void gemm_bt(
    const unsigned short* __restrict__ A, const unsigned short* __restrict__ B,
    float* __restrict__ C, const float* __restrict__ bias, int K, int ldC) {
  __shared__ __align__(16) unsigned short sA[128 * 32];
  __shared__ __align__(16) unsigned short sB[128 * 32];

  const int tid = threadIdx.x;
  const int lane = tid & 63;
  const int w = tid >> 6;
  const int wr = w >> 1;
  const int wc = w & 1;
  const long mBase = (long)blockIdx.x * 128;
  const long nBase = (long)blockIdx.y * 128;

  const unsigned short* Ati = A + mBase * K;
  const unsigned short* Bti = B + nBase * K;

  const int srow0 = w * 32;
  const int sr = lane >> 2;
  const int ske = (lane & 3) * 8;

  f32x4 acc[4][4] = {};

  for (int kt = 0; kt < K; kt += 32) {
    __syncthreads();
#pragma unroll
    for (int i = 0; i < 2; ++i) {
      const int r = srow0 + i * 16;
      __builtin_amdgcn_global_load_lds(
          (const __attribute__((address_space(1))) unsigned int*)(
              Ati + (long)(r + sr) * K + kt + ske),
          (__attribute__((address_space(3))) unsigned int*)(&sA[r * 32]),
          16, 0, 0);
      __builtin_amdgcn_global_load_lds(
          (const __attribute__((address_space(1))) unsigned int*)(
              Bti + (long)(r + sr) * K + kt + ske),
          (__attribute__((address_space(3))) unsigned int*)(&sB[r * 32]),
          16, 0, 0);
    }
    __syncthreads();

    bf16x8 af[4], bfr[4];
#pragma unroll
    for (int mi = 0; mi < 4; ++mi)
      af[mi] = *(const bf16x8*)&sA[(wr * 64 + mi * 16 + (lane & 15)) * 32 +
                                   8 * (lane >> 4)];
#pragma unroll
    for (int ni = 0; ni < 4; ++ni)
      bfr[ni] = *(const bf16x8*)&sB[(wc * 64 + ni * 16 + (lane & 15)) * 32 +
                                    8 * (lane >> 4)];
#pragma unroll
    for (int mi = 0; mi < 4; ++mi)
#pragma unroll
      for (int ni = 0; ni < 4; ++ni)
        acc[mi][ni] = __builtin_amdgcn_mfma_f32_16x16x32_bf16(
            af[mi], bfr[ni], acc[mi][ni], 0, 0, 0);
  }

  const int rq = lane >> 4;
  const int cl = lane & 15;
#pragma unroll
  for (int ni = 0; ni < 4; ++ni) {
    const long c = nBase + wc * 64 + ni * 16 + cl;
    const float bv = bias ? bias[c] : 0.0f;
#pragma unroll
    for (int mi = 0; mi < 4; ++mi) {
      const long r = mBase + wr * 64 + mi * 16 + rq * 4;
#pragma unroll
      for (int j = 0; j < 4; ++j)
        C[(r + j) * (long)ldC + c] = acc[mi][ni][j] + bv;
    }
  }
}

// ---------- 256x256 phase-interleaved NT GEMM (big output projection) ----------
// BM=BN=256, BK=64, 512 threads = 8 waves (2 wave-rows x 4 wave-cols), each
// wave computes 128x64 via 8x4 frags of mfma_f32_16x16x32_bf16.
// LDS: [dbuf 2][A/B][ksub 2] planes of [256 rows][32 bf16 cols] (64-B rows).
// Plane reads hit all 8 bank-quads evenly (8 lanes each) -> conflict-free
// without swizzle (m201's 16-way conflict came from 128-B row stride).
// Schedule: 4 phases per K-tile (quadrant = ksub x n-half), counted vmcnt(6)
// once per K-tile at P4 -> 3 half-planes stay in flight across barriers.
// Raw s_barrier only; __syncthreads' vmcnt(0) drain would kill the pipeline.
__global__ __launch_bounds__(512, 2) void gemm256_bt(
    const unsigned short* __restrict__ A,  // [M][K] bf16, K-contiguous
    const unsigned short* __restrict__ B,  // [N][K] bf16, K-contiguous
    float* __restrict__ C,                 // [M][ldC] fp32
    const float* __restrict__ bias,        // [>=N] fp32 or nullptr
    int K, int ldC) {
  __shared__ __align__(16) unsigned short lds[2][2][2][256 * 32];  // 128 KiB

  const int tid = threadIdx.x;
  const int lane = tid & 63;
  const int w = tid >> 6;  // wave 0..7 (wave-uniform)
  const int wr = w >> 2;   // 0..1
  const int wc = w & 3;    // 0..3
  const long mBase = (long)blockIdx.x * 256;
  const long nBase = (long)blockIdx.y * 256;
  const int NT = K >> 6;  // K-tiles of 64

  // stage one 16KB half-plane (256 rows x 32 cols bf16): 2 x global_load_lds,
  // each wave covers 16 rows per round (64 lanes x 16B = 1KB), LDS dest is
  // wave-uniform base + lane*16 (linear), matching row=j*128+w*16+(l>>2),
  // kcol=(l&3)*8 on the global side.
  auto stage = [&](const unsigned short* __restrict__ G, long rBase, int kcol0,
                   unsigned short* dplane) {
#pragma unroll
    for (int j = 0; j < 2; ++j) {
      const unsigned short* src = G +
          (rBase + j * 128 + w * 16 + (lane >> 2)) * (long)K + kcol0 +
          (lane & 3) * 8;
      __builtin_amdgcn_global_load_lds(
          (const __attribute__((address_space(1))) unsigned int*)src,
          (__attribute__((address_space(3))) unsigned int*)(
              dplane + (j * 128 + w * 16) * 32),
          16, 0, 0);
    }
  };

  f32x4 acc[8][4] = {};

  // ---- prologue: tile0 fully + tile1 {A_k0,B_k0,A_k1}; wait 8 oldest ----
  stage(A, mBase, 0, &lds[0][0][0][0]);
  stage(B, nBase, 0, &lds[0][1][0][0]);
  stage(A, mBase, 32, &lds[0][0][1][0]);
  stage(B, nBase, 32, &lds[0][1][1][0]);
  if (NT > 1) {
    stage(A, mBase, 64, &lds[1][0][0][0]);
    stage(B, nBase, 64, &lds[1][1][0][0]);
    stage(A, mBase, 96, &lds[1][0][1][0]);
  }
  asm volatile("s_waitcnt vmcnt(6)" ::: "memory");
  __builtin_amdgcn_s_barrier();

  for (int t = 0; t < NT; ++t) {
    const int cur = t & 1;
    bf16x8 af[8], b0, b1;

    // ---- P1: ksub=0, n-half=0; stage B_k1(t+1) -> buf[cur^1] ----
#pragma unroll
    for (int mi = 0; mi < 8; ++mi)
      af[mi] = *(const bf16x8*)&lds[cur][0][0][(wr * 128 + mi * 16 +
                                                (lane & 15)) * 32 +
                                               (lane >> 4) * 8];
    b0 = *(const bf16x8*)&lds[cur][1][0][(wc * 64 + (lane & 15)) * 32 +
                                         (lane >> 4) * 8];
    b1 = *(const bf16x8*)&lds[cur][1][0][(wc * 64 + 16 + (lane & 15)) * 32 +
                                         (lane >> 4) * 8];
    if (t + 1 < NT) stage(B, nBase, ((t + 1) << 6) + 32, &lds[cur ^ 1][1][1][0]);
    __builtin_amdgcn_s_barrier();
    __builtin_amdgcn_s_setprio(1);
#pragma unroll
    for (int mi = 0; mi < 8; ++mi)
      acc[mi][0] = __builtin_amdgcn_mfma_f32_16x16x32_bf16(af[mi], b0,
                                                           acc[mi][0], 0, 0, 0);
#pragma unroll
    for (int mi = 0; mi < 8; ++mi)
      acc[mi][1] = __builtin_amdgcn_mfma_f32_16x16x32_bf16(af[mi], b1,
                                                           acc[mi][1], 0, 0, 0);
    __builtin_amdgcn_s_setprio(0);
    __builtin_amdgcn_s_barrier();

    // ---- P2: ksub=0, n-half=1 (af reused); stage A_k0(t+2) -> buf[cur] ----
    b0 = *(const bf16x8*)&lds[cur][1][0][(wc * 64 + 32 + (lane & 15)) * 32 +
                                         (lane >> 4) * 8];
    b1 = *(const bf16x8*)&lds[cur][1][0][(wc * 64 + 48 + (lane & 15)) * 32 +
                                         (lane >> 4) * 8];
    if (t + 2 < NT) stage(A, mBase, (t + 2) << 6, &lds[cur][0][0][0]);
    __builtin_amdgcn_s_barrier();
    __builtin_amdgcn_s_setprio(1);
#pragma unroll
    for (int mi = 0; mi < 8; ++mi)
      acc[mi][2] = __builtin_amdgcn_mfma_f32_16x16x32_bf16(af[mi], b0,
                                                           acc[mi][2], 0, 0, 0);
#pragma unroll
    for (int mi = 0; mi < 8; ++mi)
      acc[mi][3] = __builtin_amdgcn_mfma_f32_16x16x32_bf16(af[mi], b1,
                                                           acc[mi][3], 0, 0, 0);
    __builtin_amdgcn_s_setprio(0);
    __builtin_amdgcn_s_barrier();

    // ---- P3: ksub=1, n-half=0; stage B_k0(t+2) -> buf[cur] ----
#pragma unroll
    for (int mi = 0; mi < 8; ++mi)
      af[mi] = *(const bf16x8*)&lds[cur][0][1][(wr * 128 + mi * 16 +
                                                (lane & 15)) * 32 +
                                               (lane >> 4) * 8];
    b0 = *(const bf16x8*)&lds[cur][1][1][(wc * 64 + (lane & 15)) * 32 +
                                         (lane >> 4) * 8];
    b1 = *(const bf16x8*)&lds[cur][1][1][(wc * 64 + 16 + (lane & 15)) * 32 +
                                         (lane >> 4) * 8];
    if (t + 2 < NT) stage(B, nBase, (t + 2) << 6, &lds[cur][1][0][0]);
    __builtin_amdgcn_s_barrier();
    __builtin_amdgcn_s_setprio(1);
#pragma unroll
    for (int mi = 0; mi < 8; ++mi)
      acc[mi][0] = __builtin_amdgcn_mfma_f32_16x16x32_bf16(af[mi], b0,
                                                           acc[mi][0], 0, 0, 0);
#pragma unroll
    for (int mi = 0; mi < 8; ++mi)
      acc[mi][1] = __builtin_amdgcn_mfma_f32_16x16x32_bf16(af[mi], b1,
                                                           acc[mi][1], 0, 0, 0);
    __builtin_amdgcn_s_setprio(0);
    __builtin_amdgcn_s_barrier();

    // ---- P4: ksub=1, n-half=1; stage A_k1(t+2); vmcnt(6) once/K-tile ----
    b0 = *(const bf16x8*)&lds[cur][1][1][(wc * 64 + 32 + (lane & 15)) * 32 +
                                         (lane >> 4) * 8];
    b1 = *(const bf16x8*)&lds[cur][1][1][(wc * 64 + 48 + (lane & 15)) * 32 +
                                         (lane >> 4) * 8];
    if (t + 2 < NT) stage(A, mBase, ((t + 2) << 6) + 32, &lds[cur][0][1][0]);
    asm volatile("s_waitcnt vmcnt(6)" ::: "memory");
    __builtin_amdgcn_s_barrier();
    __builtin_amdgcn_s_setprio(1);
#pragma unroll
    for (int mi = 0; mi < 8; ++mi)
      acc[mi][2] = __builtin_amdgcn_mfma_f32_16x16x32_bf16(af[mi], b0,
                                                           acc[mi][2], 0, 0, 0);
#pragma unroll
    for (int mi = 0; mi < 8; ++mi)
      acc[mi][3] = __builtin_amdgcn_mfma_f32_16x16x32_bf16(af[mi], b1,
                                                           acc[mi][3], 0, 0, 0);
    __builtin_amdgcn_s_setprio(0);
    __builtin_amdgcn_s_barrier();
  }

  // ---- epilogue: C/D frag mapping col=lane&15, row=4*(lane>>4)+reg [m89] ----
  const int rq = lane >> 4;
  const int cl = lane & 15;
#pragma unroll
  for (int ni = 0; ni < 4; ++ni) {
    const long c = nBase + wc * 64 + ni * 16 + cl;
    const float bv = bias ? bias[c] : 0.0f;
#pragma unroll
    for (int mi = 0; mi < 8; ++mi) {
      const long r = mBase + wr * 128 + mi * 16 + rq * 4;
#pragma unroll
      for (int j = 0; j < 4; ++j)
        C[(r + j) * (long)ldC + c] = acc[mi][ni][j] + bv;
    }
  }
}

// ---------- causal cumulative mean (chunked scan) ----------
__global__ void chunk_sums(const float* __restrict__ V,
                           float* __restrict__ part) {
  const int bc = blockIdx.x;
  const int b = bc >> 7;
  const int c = bc & (NC - 1);
  const int d0 = threadIdx.x * 4;
  const float* vp = V + ((size_t)b * SEQ + (size_t)c * CL) * DIMS + d0;
  float4 s = {0.f, 0.f, 0.f, 0.f};
#pragma unroll
  for (int l = 0; l < CL; ++l) {
    float4 v = *(const float4*)(vp + (size_t)l * DIMS);
    s.x += v.x; s.y += v.y; s.z += v.z; s.w += v.w;
  }
  float* pp = part + ((size_t)b * DIMS + d0) * NC + c;
  pp[0 * NC] = s.x; pp[1 * NC] = s.y; pp[2 * NC] = s.z; pp[3 * NC] = s.w;
}

__global__ void chunk_scan(float* __restrict__ part) {
  const int g = blockIdx.x * blockDim.x + threadIdx.x;
  float* p = part + (size_t)g * NC;
  float run = 0.f;
#pragma unroll 4
  for (int c = 0; c < NC; ++c) {
    float t = p[c];
    p[c] = run;
    run += t;
  }
}

__global__ void cum_avg(const float* __restrict__ V,
                        const float* __restrict__ part,
                        unsigned short* __restrict__ avgB) {
  const int bc = blockIdx.x;
  const int b = bc >> 7;
  const int c = bc & (NC - 1);
  const int d0 = threadIdx.x * 4;
  const float* pp = part + ((size_t)b * DIMS + d0) * NC + c;
  float4 run = {pp[0 * NC], pp[1 * NC], pp[2 * NC], pp[3 * NC]};
  const float* vp = V + ((size_t)b * SEQ + (size_t)c * CL) * DIMS + d0;
  unsigned short* op = avgB + ((size_t)b * SEQ + (size_t)c * CL) * DIMS + d0;
#pragma unroll
  for (int l = 0; l < CL; ++l) {
    float4 v = *(const float4*)(vp + (size_t)l * DIMS);
    run.x += v.x; run.y += v.y; run.z += v.z; run.w += v.w;
    const float inv = 1.0f / (float)(c * CL + l + 1);
    ushort4 o = {f2bf(run.x * inv), f2bf(run.y * inv), f2bf(run.z * inv),
                 f2bf(run.w * inv)};
    *(ushort4*)(op + (size_t)l * DIMS) = o;
  }
}

// ---------- workspace layout (bytes, 256-aligned) ----------
#define WS_EB 0UL                   // bf16 [4096][1024]   8,388,608
#define WS_WV 8388608UL             // bf16 [1024][1024]   2,097,152
#define WS_WO 10485760UL            // bf16 [32000][1024] 65,536,000
#define WS_V 76021760UL             // f32  [4096][1024]  16,777,216
#define WS_AVG 92798976UL           // bf16 [4096][1024]   8,388,608
#define WS_PART 101187584UL         // f32  [2][1024][128] 1,048,576
#define WS_NEED 102236160UL

extern "C" void kernel_launch(void* const* d_in, const int* in_sizes, int n_in,
                              void* d_out, int out_size, void* d_ws,
                              size_t ws_size, hipStream_t stream) {
  const int* idx = (const int*)d_in[0];
  const float* emb = (const float*)d_in[1];
  const float* W_V = (const float*)d_in[2];
  const float* W_out = (const float*)d_in[3];
  const float* b_out = (const float*)d_in[4];
  float* out = (float*)d_out;

  if (ws_size < WS_NEED) return;

  char* ws = (char*)d_ws;
  unsigned short* eB = (unsigned short*)(ws + WS_EB);
  unsigned short* wvB = (unsigned short*)(ws + WS_WV);
  unsigned short* woB = (unsigned short*)(ws + WS_WO);
  float* V = (float*)(ws + WS_V);
  unsigned short* avgB = (unsigned short*)(ws + WS_AVG);
  float* part = (float*)(ws + WS_PART);

  hipLaunchKernelGGL(cvt_f32_bf16, dim3(1024), dim3(256), 0, stream, W_V, wvB,
                     (DIMS * DIMS) / 4);
  hipLaunchKernelGGL(cvt_f32_bf16, dim3(2048), dim3(256), 0, stream, W_out,
                     woB, (VOCAB * DIMS) / 4);
  hipLaunchKernelGGL(gather_emb, dim3(ROWS), dim3(256), 0, stream, idx, emb,
                     eB);
  // V = e @ W_V^T  (M=4096, N=1024, K=1024) — old 128^2 kernel, 256 blocks
  hipLaunchKernelGGL(gemm_bt, dim3(ROWS / 128, DIMS / 128), dim3(256), 0,
                     stream, eB, wvB, V, (const float*)nullptr, DIMS, DIMS);
  hipLaunchKernelGGL(chunk_sums, dim3(BATCH * NC), dim3(256), 0, stream, V,
                     part);
  hipLaunchKernelGGL(chunk_scan, dim3((BATCH * DIMS) / 256), dim3(256), 0,
                     stream, part);
  hipLaunchKernelGGL(cum_avg, dim3(BATCH * NC), dim3(256), 0, stream, V, part,
                     avgB);
  // out = avg @ W_out^T + b_out  (M=4096, N=32000, K=1024)
  // 256^2 phase-interleaved kernel; grid x = m-tiles (16, fastest) keeps the
  // concurrent B working set ~8 MB so W_out streams once.
  hipLaunchKernelGGL(gemm256_bt, dim3(ROWS / 256, VOCAB / 256), dim3(512), 0,
                     stream, avgB, woB, out, b_out, DIMS, VOCAB);
}

// Round 4
// 487.580 us; speedup vs baseline: 1.1301x; 1.0369x over previous
//
#include <hip/hip_runtime.h>
#include <hip/hip_bf16.h>

typedef __attribute__((ext_vector_type(4))) float f32x4;
typedef __attribute__((ext_vector_type(8))) short bf16x8;

#define VOCAB 32000
#define DIMS 1024
#define BATCH 2
#define SEQ 2048
#define ROWS (BATCH * SEQ)  // 4096
#define NC 128              // cumsum chunks per sequence
#define CL 16               // chunk length; NC*CL == SEQ

// ---------- helpers ----------
static __device__ __forceinline__ unsigned short f2bf(float f) {
  unsigned int u = __float_as_uint(f);
  unsigned int r = u + 0x7fffu + ((u >> 16) & 1u);
  return (unsigned short)(r >> 16);
}

// ---------- fp32 -> bf16 bulk convert ----------
__global__ void cvt_f32_bf16(const float* __restrict__ src,
                             unsigned short* __restrict__ dst, int n4) {
  int i = blockIdx.x * blockDim.x + threadIdx.x;
  int stride = gridDim.x * blockDim.x;
  for (; i < n4; i += stride) {
    float4 v = ((const float4*)src)[i];
    ushort4 o = {f2bf(v.x), f2bf(v.y), f2bf(v.z), f2bf(v.w)};
    ((ushort4*)dst)[i] = o;
  }
}

// ---------- embedding gather + convert ----------
__global__ void gather_emb(const int* __restrict__ idx,
                           const float* __restrict__ emb,
                           unsigned short* __restrict__ eB) {
  const int row = blockIdx.x;
  const int t = threadIdx.x;
  const int token = idx[row];
  const float4* src = (const float4*)(emb + (size_t)token * DIMS);
  float4 v = src[t];
  ushort4 o = {f2bf(v.x), f2bf(v.y), f2bf(v.z), f2bf(v.w)};
  ((ushort4*)(eB + (size_t)row * DIMS))[t] = o;
}

// ---------- old 128x128 NT GEMM (kept for the small V projection) ----------
__global__ __launch_bounds__(256) void gemm_bt(
    const unsigned short* __restrict__ A, const unsigned short* __restrict__ B,
    float* __restrict__ C, const float* __restrict__ bias, int K, int ldC) {
  __shared__ __align__(16) unsigned short sA[128 * 32];
  __shared__ __align__(16) unsigned short sB[128 * 32];

  const int tid = threadIdx.x;
  const int lane = tid & 63;
  const int w = tid >> 6;
  const int wr = w >> 1;
  const int wc = w & 1;
  const long mBase = (long)blockIdx.x * 128;
  const long nBase = (long)blockIdx.y * 128;

  const unsigned short* Ati = A + mBase * K;
  const unsigned short* Bti = B + nBase * K;

  const int srow0 = w * 32;
  const int sr = lane >> 2;
  const int ske = (lane & 3) * 8;

  f32x4 acc[4][4] = {};

  for (int kt = 0; kt < K; kt += 32) {
    __syncthreads();
#pragma unroll
    for (int i = 0; i < 2; ++i) {
      const int r = srow0 + i * 16;
      __builtin_amdgcn_global_load_lds(
          (const __attribute__((address_space(1))) unsigned int*)(
              Ati + (long)(r + sr) * K + kt + ske),
          (__attribute__((address_space(3))) unsigned int*)(&sA[r * 32]),
          16, 0, 0);
      __builtin_amdgcn_global_load_lds(
          (const __attribute__((address_space(1))) unsigned int*)(
              Bti + (long)(r + sr) * K + kt + ske),
          (__attribute__((address_space(3))) unsigned int*)(&sB[r * 32]),
          16, 0, 0);
    }
    __syncthreads();

    bf16x8 af[4], bfr[4];
#pragma unroll
    for (int mi = 0; mi < 4; ++mi)
      af[mi] = *(const bf16x8*)&sA[(wr * 64 + mi * 16 + (lane & 15)) * 32 +
                                   8 * (lane >> 4)];
#pragma unroll
    for (int ni = 0; ni < 4; ++ni)
      bfr[ni] = *(const bf16x8*)&sB[(wc * 64 + ni * 16 + (lane & 15)) * 32 +
                                    8 * (lane >> 4)];
#pragma unroll
    for (int mi = 0; mi < 4; ++mi)
#pragma unroll
      for (int ni = 0; ni < 4; ++ni)
        acc[mi][ni] = __builtin_amdgcn_mfma_f32_16x16x32_bf16(
            af[mi], bfr[ni], acc[mi][ni], 0, 0, 0);
  }

  const int rq = lane >> 4;
  const int cl = lane & 15;
#pragma unroll
  for (int ni = 0; ni < 4; ++ni) {
    const long c = nBase + wc * 64 + ni * 16 + cl;
    const float bv = bias ? bias[c] : 0.0f;
#pragma unroll
    for (int mi = 0; mi < 4; ++mi) {
      const long r = mBase + wr * 64 + mi * 16 + rq * 4;
#pragma unroll
      for (int j = 0; j < 4; ++j)
        C[(r + j) * (long)ldC + c] = acc[mi][ni][j] + bv;
    }
  }
}

// ---------- 256x256 phase-interleaved NT GEMM (big output projection) ----------
// BM=BN=256, BK=64, 512 threads = 8 waves (2x4), each wave 128x64 via 8x4
// frags of mfma_f32_16x16x32_bf16.
// LDS: [dbuf 2][A/B][ksub 2] planes of [256 rows][32 bf16] (64-B rows).
// XOR-swizzle (T2-analog, rule #21 both-sides): LDS element block b (of 4x
// 8-elem blocks per row) at row r holds GLOBAL k-block b ^ ((r>>1)&3).
//  - stage: LDS dest linear (global_load_lds requirement); global SOURCE
//    column pre-swizzled per-lane.
//  - frag read: element offset = row*32 + (((lane>>4)*8) ^ (((row>>1)&3)<<3)).
//    Issue-groups of 8 lanes then cover all 8 bank-quads exactly once
//    (slot = ((r&1)<<2)|(q^((r>>1)&3)) is bijective over r=0..7) -> the
//    round-3 4-way conflict (2.46e7 cycles) goes away.
// Schedule: 4 phases/K-tile, counted vmcnt(6) once per K-tile at P4, raw
// s_barrier only (no __syncthreads vmcnt(0) drain), setprio(1) around MFMA.
__global__ __launch_bounds__(512, 2) void gemm256_bt(
    const unsigned short* __restrict__ A,  // [M][K] bf16, K-contiguous
    const unsigned short* __restrict__ B,  // [N][K] bf16, K-contiguous
    float* __restrict__ C,                 // [M][ldC] fp32
    const float* __restrict__ bias,        // [>=N] fp32 or nullptr
    int K, int ldC) {
  __shared__ __align__(16) unsigned short lds[2][2][2][256 * 32];  // 128 KiB

  const int tid = threadIdx.x;
  const int lane = tid & 63;
  const int w = tid >> 6;  // wave 0..7 (wave-uniform)
  const int wr = w >> 2;   // 0..1
  const int wc = w & 3;    // 0..3
  const long mBase = (long)blockIdx.x * 256;
  const long nBase = (long)blockIdx.y * 256;
  const int NT = K >> 6;  // K-tiles of 64

  // read-side swizzle constants (per-lane)
  const int rl = lane & 15;                       // row-within-16
  const int koffR = ((lane >> 4) * 8) ^ (((rl >> 1) & 3) << 3);
  // stage-side swizzled global k-element offset
  const int skel = ((lane & 3) * 8) ^ (((lane >> 3) & 3) << 3);

  // stage one 16KB half-plane (256 rows x 32 cols bf16): 2 x global_load_lds.
  // LDS dest linear: lane l -> row (l>>2), element block (l&3). Global source
  // column = skel (pre-swizzled) so swizzled READ returns the right data.
  auto stage = [&](const unsigned short* __restrict__ G, long rBase, int kcol0,
                   unsigned short* dplane) {
#pragma unroll
    for (int j = 0; j < 2; ++j) {
      const unsigned short* src = G +
          (rBase + j * 128 + w * 16 + (lane >> 2)) * (long)K + kcol0 + skel;
      __builtin_amdgcn_global_load_lds(
          (const __attribute__((address_space(1))) unsigned int*)src,
          (__attribute__((address_space(3))) unsigned int*)(
              dplane + (j * 128 + w * 16) * 32),
          16, 0, 0);
    }
  };

  f32x4 acc[8][4] = {};

  // ---- prologue: tile0 fully + tile1 {A_k0,B_k0,A_k1}; wait 8 oldest ----
  stage(A, mBase, 0, &lds[0][0][0][0]);
  stage(B, nBase, 0, &lds[0][1][0][0]);
  stage(A, mBase, 32, &lds[0][0][1][0]);
  stage(B, nBase, 32, &lds[0][1][1][0]);
  if (NT > 1) {
    stage(A, mBase, 64, &lds[1][0][0][0]);
    stage(B, nBase, 64, &lds[1][1][0][0]);
    stage(A, mBase, 96, &lds[1][0][1][0]);
  }
  asm volatile("s_waitcnt vmcnt(6)" ::: "memory");
  __builtin_amdgcn_s_barrier();

  for (int t = 0; t < NT; ++t) {
    const int cur = t & 1;
    bf16x8 af[8], b0, b1;

    // ---- P1: ksub=0, n-half=0; stage B_k1(t+1) -> buf[cur^1] ----
#pragma unroll
    for (int mi = 0; mi < 8; ++mi)
      af[mi] = *(const bf16x8*)&lds[cur][0][0][(wr * 128 + mi * 16 + rl) * 32 +
                                               koffR];
    b0 = *(const bf16x8*)&lds[cur][1][0][(wc * 64 + rl) * 32 + koffR];
    b1 = *(const bf16x8*)&lds[cur][1][0][(wc * 64 + 16 + rl) * 32 + koffR];
    if (t + 1 < NT) stage(B, nBase, ((t + 1) << 6) + 32, &lds[cur ^ 1][1][1][0]);
    __builtin_amdgcn_s_barrier();
    __builtin_amdgcn_s_setprio(1);
#pragma unroll
    for (int mi = 0; mi < 8; ++mi)
      acc[mi][0] = __builtin_amdgcn_mfma_f32_16x16x32_bf16(af[mi], b0,
                                                           acc[mi][0], 0, 0, 0);
#pragma unroll
    for (int mi = 0; mi < 8; ++mi)
      acc[mi][1] = __builtin_amdgcn_mfma_f32_16x16x32_bf16(af[mi], b1,
                                                           acc[mi][1], 0, 0, 0);
    __builtin_amdgcn_s_setprio(0);
    __builtin_amdgcn_s_barrier();

    // ---- P2: ksub=0, n-half=1 (af reused); stage A_k0(t+2) -> buf[cur] ----
    b0 = *(const bf16x8*)&lds[cur][1][0][(wc * 64 + 32 + rl) * 32 + koffR];
    b1 = *(const bf16x8*)&lds[cur][1][0][(wc * 64 + 48 + rl) * 32 + koffR];
    if (t + 2 < NT) stage(A, mBase, (t + 2) << 6, &lds[cur][0][0][0]);
    __builtin_amdgcn_s_barrier();
    __builtin_amdgcn_s_setprio(1);
#pragma unroll
    for (int mi = 0; mi < 8; ++mi)
      acc[mi][2] = __builtin_amdgcn_mfma_f32_16x16x32_bf16(af[mi], b0,
                                                           acc[mi][2], 0, 0, 0);
#pragma unroll
    for (int mi = 0; mi < 8; ++mi)
      acc[mi][3] = __builtin_amdgcn_mfma_f32_16x16x32_bf16(af[mi], b1,
                                                           acc[mi][3], 0, 0, 0);
    __builtin_amdgcn_s_setprio(0);
    __builtin_amdgcn_s_barrier();

    // ---- P3: ksub=1, n-half=0; stage B_k0(t+2) -> buf[cur] ----
#pragma unroll
    for (int mi = 0; mi < 8; ++mi)
      af[mi] = *(const bf16x8*)&lds[cur][0][1][(wr * 128 + mi * 16 + rl) * 32 +
                                               koffR];
    b0 = *(const bf16x8*)&lds[cur][1][1][(wc * 64 + rl) * 32 + koffR];
    b1 = *(const bf16x8*)&lds[cur][1][1][(wc * 64 + 16 + rl) * 32 + koffR];
    if (t + 2 < NT) stage(B, nBase, (t + 2) << 6, &lds[cur][1][0][0]);
    __builtin_amdgcn_s_barrier();
    __builtin_amdgcn_s_setprio(1);
#pragma unroll
    for (int mi = 0; mi < 8; ++mi)
      acc[mi][0] = __builtin_amdgcn_mfma_f32_16x16x32_bf16(af[mi], b0,
                                                           acc[mi][0], 0, 0, 0);
#pragma unroll
    for (int mi = 0; mi < 8; ++mi)
      acc[mi][1] = __builtin_amdgcn_mfma_f32_16x16x32_bf16(af[mi], b1,
                                                           acc[mi][1], 0, 0, 0);
    __builtin_amdgcn_s_setprio(0);
    __builtin_amdgcn_s_barrier();

    // ---- P4: ksub=1, n-half=1; stage A_k1(t+2); vmcnt(6) once/K-tile ----
    b0 = *(const bf16x8*)&lds[cur][1][1][(wc * 64 + 32 + rl) * 32 + koffR];
    b1 = *(const bf16x8*)&lds[cur][1][1][(wc * 64 + 48 + rl) * 32 + koffR];
    if (t + 2 < NT) stage(A, mBase, ((t + 2) << 6) + 32, &lds[cur][0][1][0]);
    asm volatile("s_waitcnt vmcnt(6)" ::: "memory");
    __builtin_amdgcn_s_barrier();
    __builtin_amdgcn_s_setprio(1);
#pragma unroll
    for (int mi = 0; mi < 8; ++mi)
      acc[mi][2] = __builtin_amdgcn_mfma_f32_16x16x32_bf16(af[mi], b0,
                                                           acc[mi][2], 0, 0, 0);
#pragma unroll
    for (int mi = 0; mi < 8; ++mi)
      acc[mi][3] = __builtin_amdgcn_mfma_f32_16x16x32_bf16(af[mi], b1,
                                                           acc[mi][3], 0, 0, 0);
    __builtin_amdgcn_s_setprio(0);
    __builtin_amdgcn_s_barrier();
  }

  // ---- epilogue: C/D frag mapping col=lane&15, row=4*(lane>>4)+reg [m89] ----
  const int rq = lane >> 4;
  const int cl = lane & 15;
#pragma unroll
  for (int ni = 0; ni < 4; ++ni) {
    const long c = nBase + wc * 64 + ni * 16 + cl;
    const float bv = bias ? bias[c] : 0.0f;
#pragma unroll
    for (int mi = 0; mi < 8; ++mi) {
      const long r = mBase + wr * 128 + mi * 16 + rq * 4;
#pragma unroll
      for (int j = 0; j < 4; ++j)
        C[(r + j) * (long)ldC + c] = acc[mi][ni][j] + bv;
    }
  }
}

// ---------- causal cumulative mean (chunked scan) ----------
__global__ void chunk_sums(const float* __restrict__ V,
                           float* __restrict__ part) {
  const int bc = blockIdx.x;
  const int b = bc >> 7;
  const int c = bc & (NC - 1);
  const int d0 = threadIdx.x * 4;
  const float* vp = V + ((size_t)b * SEQ + (size_t)c * CL) * DIMS + d0;
  float4 s = {0.f, 0.f, 0.f, 0.f};
#pragma unroll
  for (int l = 0; l < CL; ++l) {
    float4 v = *(const float4*)(vp + (size_t)l * DIMS);
    s.x += v.x; s.y += v.y; s.z += v.z; s.w += v.w;
  }
  float* pp = part + ((size_t)b * DIMS + d0) * NC + c;
  pp[0 * NC] = s.x; pp[1 * NC] = s.y; pp[2 * NC] = s.z; pp[3 * NC] = s.w;
}

__global__ void chunk_scan(float* __restrict__ part) {
  const int g = blockIdx.x * blockDim.x + threadIdx.x;
  float* p = part + (size_t)g * NC;
  float run = 0.f;
#pragma unroll 4
  for (int c = 0; c < NC; ++c) {
    float t = p[c];
    p[c] = run;
    run += t;
  }
}

__global__ void cum_avg(const float* __restrict__ V,
                        const float* __restrict__ part,
                        unsigned short* __restrict__ avgB) {
  const int bc = blockIdx.x;
  const int b = bc >> 7;
  const int c = bc & (NC - 1);
  const int d0 = threadIdx.x * 4;
  const float* pp = part + ((size_t)b * DIMS + d0) * NC + c;
  float4 run = {pp[0 * NC], pp[1 * NC], pp[2 * NC], pp[3 * NC]};
  const float* vp = V + ((size_t)b * SEQ + (size_t)c * CL) * DIMS + d0;
  unsigned short* op = avgB + ((size_t)b * SEQ + (size_t)c * CL) * DIMS + d0;
#pragma unroll
  for (int l = 0; l < CL; ++l) {
    float4 v = *(const float4*)(vp + (size_t)l * DIMS);
    run.x += v.x; run.y += v.y; run.z += v.z; run.w += v.w;
    const float inv = 1.0f / (float)(c * CL + l + 1);
    ushort4 o = {f2bf(run.x * inv), f2bf(run.y * inv), f2bf(run.z * inv),
                 f2bf(run.w * inv)};
    *(ushort4*)(op + (size_t)l * DIMS) = o;
  }
}

// ---------- workspace layout (bytes, 256-aligned) ----------
#define WS_EB 0UL                   // bf16 [4096][1024]   8,388,608
#define WS_WV 8388608UL             // bf16 [1024][1024]   2,097,152
#define WS_WO 10485760UL            // bf16 [32000][1024] 65,536,000
#define WS_V 76021760UL             // f32  [4096][1024]  16,777,216
#define WS_AVG 92798976UL           // bf16 [4096][1024]   8,388,608
#define WS_PART 101187584UL         // f32  [2][1024][128] 1,048,576
#define WS_NEED 102236160UL

extern "C" void kernel_launch(void* const* d_in, const int* in_sizes, int n_in,
                              void* d_out, int out_size, void* d_ws,
                              size_t ws_size, hipStream_t stream) {
  const int* idx = (const int*)d_in[0];
  const float* emb = (const float*)d_in[1];
  const float* W_V = (const float*)d_in[2];
  const float* W_out = (const float*)d_in[3];
  const float* b_out = (const float*)d_in[4];
  float* out = (float*)d_out;

  if (ws_size < WS_NEED) return;

  char* ws = (char*)d_ws;
  unsigned short* eB = (unsigned short*)(ws + WS_EB);
  unsigned short* wvB = (unsigned short*)(ws + WS_WV);
  unsigned short* woB = (unsigned short*)(ws + WS_WO);
  float* V = (float*)(ws + WS_V);
  unsigned short* avgB = (unsigned short*)(ws + WS_AVG);
  float* part = (float*)(ws + WS_PART);

  hipLaunchKernelGGL(cvt_f32_bf16, dim3(1024), dim3(256), 0, stream, W_V, wvB,
                     (DIMS * DIMS) / 4);
  hipLaunchKernelGGL(cvt_f32_bf16, dim3(2048), dim3(256), 0, stream, W_out,
                     woB, (VOCAB * DIMS) / 4);
  hipLaunchKernelGGL(gather_emb, dim3(ROWS), dim3(256), 0, stream, idx, emb,
                     eB);
  // V = e @ W_V^T  (M=4096, N=1024, K=1024) — old 128^2 kernel, 256 blocks
  hipLaunchKernelGGL(gemm_bt, dim3(ROWS / 128, DIMS / 128), dim3(256), 0,
                     stream, eB, wvB, V, (const float*)nullptr, DIMS, DIMS);
  hipLaunchKernelGGL(chunk_sums, dim3(BATCH * NC), dim3(256), 0, stream, V,
                     part);
  hipLaunchKernelGGL(chunk_scan, dim3((BATCH * DIMS) / 256), dim3(256), 0,
                     stream, part);
  hipLaunchKernelGGL(cum_avg, dim3(BATCH * NC), dim3(256), 0, stream, V, part,
                     avgB);
  // out = avg @ W_out^T + b_out  (M=4096, N=32000, K=1024)
  // grid x = m-tiles (16, fastest): concurrent B working set ~8 MB,
  // W_out streams once (round-2 counter evidence).
  hipLaunchKernelGGL(gemm256_bt, dim3(ROWS / 256, VOCAB / 256), dim3(512), 0,
                     stream, avgB, woB, out, b_out, DIMS, VOCAB);
}